// Round 2
// baseline (172.112 us; speedup 1.0000x reference)
//
#include <hip/hip_runtime.h>
#include <hip/hip_bf16.h>

// MultiScaleAttention: B=1,S=2048,D=1024,H=16,DH=64,WIN=128,DIL=4.
// ESTABLISHED: inputs fp32, output fp32, ws 256 MiB.
// Round-15: 8-WAVE KEY-SPLIT attn. r14 unified kernel was latency-bound:
// Occupancy 18.7% (512 blocks x 4 waves = 8 waves/CU), MfmaUtil 14%, HBM 3%.
// Static-max softmax is a plain sum => split each tile's 64 keys across two
// wave-groups (waves 0-3: keys 0-31, waves 4-7: keys 32-63), same q-rows,
// shared K/V LDS staging; combine (o,l) partials at the end via LDS.
//  - 512 threads/block, __launch_bounds__(512,4) -> 16 waves/CU (50% occ)
//  - Q hoisted to registers (wave-fixed fragments); Qs LDS deleted
//  - within-tile key placement = identity (Ks row n = key n); group = n>>5
//  - vT kappa-map: V[seq] at 512*(seq&3) + 64*(j>>6) + 32*((j>>5)&1)
//    + 2*(j&15) + ((j>>4)&1), j=seq>>2  (PV slice contiguous per group;
//    local window = group wH's 32 keys of in-group tile wt2)
//  - dilated delta via per-slot scalar snapshots (rho loop unrolled, static)
//  - everything else (gemm/cast/transpose) byte-identical to r14 (162.4us)

typedef __attribute__((ext_vector_type(8))) short s8v;   // 8 bf16
typedef __attribute__((ext_vector_type(4))) float f4v;   // 4 fp32

#define QSCALE 0.18033688011112042f   // 0.125 * log2(e)

__device__ __forceinline__ short f2bf(float f) {
  union { float f; unsigned u; } x; x.f = f;
  unsigned r = (x.u + 0x7FFF + ((x.u >> 16) & 1)) >> 16;   // RNE
  return (short)r;
}
__device__ __forceinline__ f4v mfma16(s8v a, s8v b, f4v c) {
  return __builtin_amdgcn_mfma_f32_16x16x32_bf16(a, b, c, 0, 0, 0);
}
__device__ __forceinline__ void load_lds16(const void* g, void* l) {
  __builtin_amdgcn_global_load_lds(
      (const __attribute__((address_space(1))) unsigned int*)g,
      (__attribute__((address_space(3))) unsigned int*)l, 16, 0, 0);
}
__device__ __forceinline__ float exp2f_fast(float x) {
  return __builtin_amdgcn_exp2f(x);     // v_exp_f32: D = 2^S0
}

__global__ __launch_bounds__(256)
void fill_const_kernel(float* __restrict__ out, int n, float v) {
  int i = blockIdx.x * 256 + threadIdx.x;
  if (i < n) out[i] = v;
}

__global__ __launch_bounds__(256)
void cast_f32_bf16(const float* __restrict__ src, short* __restrict__ dst, int n) {
  int i = (blockIdx.x * 256 + threadIdx.x) * 4;
  if (i < n) {
    float4 v = *reinterpret_cast<const float4*>(&src[i]);
    union { short s[4]; int2 p; } u;
    u.s[0] = f2bf(v.x); u.s[1] = f2bf(v.y); u.s[2] = f2bf(v.z); u.s[3] = f2bf(v.w);
    *reinterpret_cast<int2*>(&dst[i]) = u.p;
  }
}

// ---------- transpose+convert: src fp32 [K][N] -> dst bf16 [N][K] ----------
__global__ __launch_bounds__(256)
void transpose_conv(const float* __restrict__ src, short* __restrict__ dst,
                    int K, int N) {
  __shared__ float T[64][69];
  const int n0 = blockIdx.x * 64, k0 = blockIdx.y * 64;
  const int t = threadIdx.x;
  for (int jb = t; jb < 1024; jb += 256) {
    int r = jb >> 4, c4 = (jb & 15) * 4;
    float4 v = *reinterpret_cast<const float4*>(&src[(size_t)(k0 + r) * N + n0 + c4]);
    T[c4 + 0][r] = v.x; T[c4 + 1][r] = v.y; T[c4 + 2][r] = v.z; T[c4 + 3][r] = v.w;
  }
  __syncthreads();
  for (int jb = t; jb < 512; jb += 256) {
    int n = jb >> 3, k8 = (jb & 7) * 8;
    union { short s[8]; int4 v; } p;
#pragma unroll
    for (int i = 0; i < 8; ++i) p.s[i] = f2bf(T[n][k8 + i]);
    *reinterpret_cast<int4*>(&dst[(size_t)(n0 + n) * K + k0 + k8]) = p.v;
  }
}

// ---------- MFMA GEMM, 64xNT tile, BK=32, C = A * Bt^T ----------
// COUT 0 (g1): C split -> qb (pre-scaled by QSCALE) / kb row-major bf16,
//              V stored to vT in the kappa-permuted layout (see header).
// COUT 1 (g2): C fp32 = acc/3 -> co.
template <int COUT, bool AF32, int NT>
__global__ __launch_bounds__(256)
void gemm_tile(const void* __restrict__ Av, const short* __restrict__ Bt,
               short* __restrict__ qb, short* __restrict__ kb,
               short* __restrict__ vT, float* __restrict__ co,
               int K, int N) {
  __shared__ __align__(16) short As[64 * 32];
  __shared__ __align__(16) short Bs[NT * 32];
  const int tid = threadIdx.x, wave = tid >> 6;
  const int li = tid & 63;
  const int row0 = blockIdx.y * 64, col0 = blockIdx.x * NT;
  const int lr = li & 15, quad = li >> 4, lk = quad * 8;
  constexpr int NTW = NT / 64;          // n-16-tiles per wave (2 or 1)

  f4v acc[4][NTW];
#pragma unroll
  for (int i = 0; i < 4; ++i)
#pragma unroll
    for (int j = 0; j < NTW; ++j) acc[i][j] = (f4v){0.f, 0.f, 0.f, 0.f};

  for (int k0 = 0; k0 < K; k0 += 32) {
    __syncthreads();
#pragma unroll
    for (int u = 0; u < NTW; ++u)
      load_lds16(Bt + (size_t)(col0 + u * 64 + (tid >> 2)) * K + k0 + (tid & 3) * 8,
                 &Bs[u * 2048 + wave * 512]);
    if (AF32) {
      const float* A = (const float*)Av;
#pragma unroll
      for (int c = 0; c < 2; ++c) {
        int j = c * 256 + tid;           // 512 float4 chunks
        int r = j >> 3, c4 = (j & 7) * 4;
        float4 v = *reinterpret_cast<const float4*>(&A[(size_t)(row0 + r) * K + k0 + c4]);
        union { short s[4]; int2 v2; } p;
        p.s[0] = f2bf(v.x); p.s[1] = f2bf(v.y); p.s[2] = f2bf(v.z); p.s[3] = f2bf(v.w);
        *reinterpret_cast<int2*>(&As[r * 32 + c4]) = p.v2;
      }
    } else {
      load_lds16((const short*)Av + (size_t)(row0 + (tid >> 2)) * K + k0 + (tid & 3) * 8,
                 &As[wave * 512]);
    }
    __syncthreads();

    s8v af[4], bfr[NTW];
#pragma unroll
    for (int mt = 0; mt < 4; ++mt)
      af[mt] = *reinterpret_cast<const s8v*>(&As[(mt * 16 + lr) * 32 + lk]);
#pragma unroll
    for (int u = 0; u < NTW; ++u)
      bfr[u] = *reinterpret_cast<const s8v*>(&Bs[(wave * (NT / 4) + u * 16 + lr) * 32 + lk]);
#pragma unroll
    for (int mt = 0; mt < 4; ++mt)
#pragma unroll
      for (int u = 0; u < NTW; ++u)
        acc[mt][u] = mfma16(af[mt], bfr[u], acc[mt][u]);
  }

  // epilogue: C/D layout col=lane&15, row=quad*4+reg
#pragma unroll
  for (int mt = 0; mt < 4; ++mt) {
#pragma unroll
    for (int u = 0; u < NTW; ++u) {
      int gcol = col0 + wave * (NT / 4) + u * 16 + lr;
      int grow0 = row0 + mt * 16 + quad * 4;
      if (COUT == 0) {
        if (gcol >= 2048) {              // vT, kappa-permuted layout
          int d = gcol - 2048;
          int j = grow0 >> 2;            // in-residue position; residue = r
          int gb = ((j >> 6) << 6) + (((j >> 5) & 1) << 5) +
                   ((j & 15) << 1) + ((j >> 4) & 1);
          size_t base = (size_t)d * 2048 + gb;
#pragma unroll
          for (int r = 0; r < 4; ++r)
            vT[base + (r << 9)] = f2bf(acc[mt][u][r]);
        } else {
          short* dst = (gcol < 1024) ? qb : kb;
          float sc = (gcol < 1024) ? QSCALE : 1.0f;
          int c = gcol & 1023;
#pragma unroll
          for (int r = 0; r < 4; ++r)
            dst[(size_t)(grow0 + r) * 1024 + c] = f2bf(acc[mt][u][r] * sc);
        }
      } else {
#pragma unroll
        for (int r = 0; r < 4; ++r)
          co[(size_t)(grow0 + r) * N + gcol] = acc[mt][u][r] * (1.0f / 3.0f);
      }
    }
  }
}

// ---------- unified flash attention, 8-wave key-split -----------------------
// 512 blocks (h=b&15, g=b>>4), 512 threads = 8 waves.
// grp = wave>>2 owns keys [grp*32, +32) of every tile; wr = wave&3 owns
// q-rows g*64 + wr*16 .. +15. 32 key tiles, residue-major (tile t: residue
// rho=t>>3, in-group tile t&7; Ks row n = key n, seq = 4*((t&7)*64+n)+rho).
// Pls col (per group) = 2*lr + u for key n=(2*grp+u)*16+lr; Vt cols match.
// Dilated = per-rho accumulator delta on slot r==rho; local = group wH's
// 32 keys of in-group tile wt2=g>>2 (extra mfma(a,b,0) on 4 tiles).
// Partials combined across wave-group pairs via LDS at the end.
__global__ __launch_bounds__(512, 4)
void attn_unified(const short* __restrict__ qb, const short* __restrict__ kb,
                  const short* __restrict__ vT, short* __restrict__ o) {
  __shared__ __align__(16) short Ks[2][64][72];
  __shared__ __align__(16) short Vt[2][64][72];   // [d][kappa]
  __shared__ __align__(16) short Pls[8][16][40];  // per-wave P: 16 rows x 32
  __shared__ float lX[2][4][4][12];               // [grp][wr][quad][l partials]

  const int tid = threadIdx.x;
  const int wave = tid >> 6, li = tid & 63;
  const int grp = wave >> 2, wr = wave & 3;
  const int b = blockIdx.x, h = b & 15, g = b >> 4;
  const int qcol = h * 64;
  const int lr = li & 15, quad = li >> 4, lk = quad * 8;
  const int wt2 = g >> 2;            // in-group tile holding the local window
  const int wH  = (g >> 1) & 1;      // which key-group holds the window
  const bool wgrp = (grp == wH);
  const int sr = tid >> 3, sc8 = (tid & 7) * 8;   // staging row / col

  // Q fragments in registers (qb pre-scaled by QSCALE at g1)
  s8v q0, q1;
  {
    const short* qrow = &qb[(size_t)(g * 64 + wr * 16 + lr) * 1024 + qcol];
    q0 = *reinterpret_cast<const s8v*>(&qrow[lk]);
    q1 = *reinterpret_cast<const s8v*>(&qrow[32 + lk]);
  }

  // stage tile 0 (rho=0, in-group tile 0): one int4 K + one int4 V per thread
  *reinterpret_cast<int4*>(&Ks[0][sr][sc8]) =
      *reinterpret_cast<const int4*>(&kb[(size_t)(sr << 2) * 1024 + qcol + sc8]);
  *reinterpret_cast<int4*>(&Vt[0][sr][sc8]) =
      *reinterpret_cast<const int4*>(&vT[(size_t)(h * 64 + sr) * 2048 + sc8]);
  __syncthreads();

  float l_r[4]   = {0.f, 0.f, 0.f, 0.f};
  float l_loc[4] = {0.f, 0.f, 0.f, 0.f};
  float l_dil[4] = {0.f, 0.f, 0.f, 0.f};
  f4v oacc[4], o_loc[4], o_dil[4];
#pragma unroll
  for (int i = 0; i < 4; ++i) {
    oacc[i]  = (f4v){0.f, 0.f, 0.f, 0.f};
    o_loc[i] = (f4v){0.f, 0.f, 0.f, 0.f};
    o_dil[i] = (f4v){0.f, 0.f, 0.f, 0.f};
  }

  // lane-constant LDS byte offsets (in shorts)
  const int koffA = ((grp * 2 + 0) * 16 + lr) * 72 + lk;
  const int koffB = ((grp * 2 + 1) * 16 + lr) * 72 + lk;
  const short* KsF = &Ks[0][0][0];
  const short* VtF = &Vt[0][0][0];

#pragma unroll
  for (int rho = 0; rho < 4; ++rho) {
    // snapshot for the dilated delta (slot rho only; static index)
    const float sn0 = oacc[0][rho], sn1 = oacc[1][rho],
                sn2 = oacc[2][rho], sn3 = oacc[3][rho];
    const float lsn = l_r[rho];

#pragma unroll 2
    for (int t8 = 0; t8 < 8; ++t8) {
      const int t = rho * 8 + t8;
      const int cur = t8 & 1, nxt = cur ^ 1;
      const bool pf = (rho < 3) || (t8 < 7);
      const bool wt = wgrp && (t8 == wt2);
      const int cb = cur * 4608;        // 64*72 shorts per buffer

      // prefetch tile t+1 into registers (overlaps compute below)
      int4 kpre, vpre;
      if (pf) {
        const int tn = t + 1;
        const int ksn = ((((tn & 7) << 6) + sr) << 2) + (tn >> 3);
        kpre = *reinterpret_cast<const int4*>(&kb[(size_t)ksn * 1024 + qcol + sc8]);
        vpre = *reinterpret_cast<const int4*>(
            &vT[(size_t)(h * 64 + sr) * 2048 + tn * 64 + sc8]);
      }

      // S = Q K^T for this group's 2 key-16-tiles (contraction over d)
      f4v s4a = (f4v){0.f, 0.f, 0.f, 0.f};
      f4v s4b = (f4v){0.f, 0.f, 0.f, 0.f};
      s4a = mfma16(q0, *reinterpret_cast<const s8v*>(&KsF[cb + koffA]), s4a);
      s4b = mfma16(q0, *reinterpret_cast<const s8v*>(&KsF[cb + koffB]), s4b);
      s4a = mfma16(q1, *reinterpret_cast<const s8v*>(&KsF[cb + koffA + 32]), s4a);
      s4b = mfma16(q1, *reinterpret_cast<const s8v*>(&KsF[cb + koffB + 32]), s4b);

      // static-max softmax: p = exp2(s); pack 2 bf16 per lane-row into Pls
#pragma unroll
      for (int r = 0; r < 4; ++r) {
        float p0 = exp2f_fast(s4a[r]), p1 = exp2f_fast(s4b[r]);
        float ps = p0 + p1;
        l_r[r] += ps;
        if (wt) l_loc[r] += ps;
        union { short s[2]; int v; } pk;
        pk.s[0] = f2bf(p0); pk.s[1] = f2bf(p1);
        *reinterpret_cast<int*>(&Pls[wave][quad * 4 + r][2 * lr]) = pk.v;
      }

      // O += P V over this group's 32 keys (contraction slice grp*32..+31)
      {
        s8v ap = *reinterpret_cast<const s8v*>(&Pls[wave][lr][lk]);
        if (wt) {
#pragma unroll
          for (int nt = 0; nt < 4; ++nt) {
            s8v bv = *reinterpret_cast<const s8v*>(
                &VtF[cb + (nt * 16 + lr) * 72 + grp * 32 + lk]);
            f4v dd = mfma16(ap, bv, (f4v){0.f, 0.f, 0.f, 0.f});
            oacc[nt] += dd;
            o_loc[nt] += dd;
          }
        } else {
#pragma unroll
          for (int nt = 0; nt < 4; ++nt) {
            s8v bv = *reinterpret_cast<const s8v*>(
                &VtF[cb + (nt * 16 + lr) * 72 + grp * 32 + lk]);
            oacc[nt] = mfma16(ap, bv, oacc[nt]);
          }
        }
      }

      // write prefetched tile into the other buffer; single barrier per tile
      if (pf) {
        *reinterpret_cast<int4*>(&Ks[nxt][sr][sc8]) = kpre;
        *reinterpret_cast<int4*>(&Vt[nxt][sr][sc8]) = vpre;
      }
      __syncthreads();
    }

    // dilated delta: q-rows in slot r==rho have residue rho
    l_dil[rho] = l_r[rho] - lsn;
    o_dil[0][rho] = oacc[0][rho] - sn0;
    o_dil[1][rho] = oacc[1][rho] - sn1;
    o_dil[2][rho] = oacc[2][rho] - sn2;
    o_dil[3][rho] = oacc[3][rho] - sn3;
  }

  // ---- epilogue: quad-reduce l's, exchange across wave-group pairs --------
  float lv[12];
#pragma unroll
  for (int r = 0; r < 4; ++r) { lv[r] = l_r[r]; lv[4 + r] = l_loc[r]; lv[8 + r] = l_dil[r]; }
#pragma unroll
  for (int k = 0; k < 12; ++k) {
    lv[k] += __shfl_xor(lv[k], 1, 16);
    lv[k] += __shfl_xor(lv[k], 2, 16);
    lv[k] += __shfl_xor(lv[k], 4, 16);
    lv[k] += __shfl_xor(lv[k], 8, 16);
  }
  if (lr == 0) {
#pragma unroll
    for (int k = 0; k < 12; ++k) lX[grp][wr][quad][k] = lv[k];
  }
  __syncthreads();

  f4v part[4];
#pragma unroll
  for (int r = 0; r < 4; ++r) {
    float lg = lX[0][wr][quad][r]     + lX[1][wr][quad][r];
    float ll = lX[0][wr][quad][4 + r] + lX[1][wr][quad][4 + r];
    float ld = lX[0][wr][quad][8 + r] + lX[1][wr][quad][8 + r];
    float ig = 1.0f / lg, il = 1.0f / ll, id = 1.0f / ld;
#pragma unroll
    for (int nt = 0; nt < 4; ++nt)
      part[nt][r] = oacc[nt][r] * ig + o_loc[nt][r] * il + o_dil[nt][r] * id;
  }

  // pair-combine the blended partials through LDS (reuse Ks region)
  float* xch = reinterpret_cast<float*>(&Ks[0][0][0]);
  const int slot = wr * 64 + li;       // 0..255, stride-18 float rows
  if (grp == 1) {
#pragma unroll
    for (int nt = 0; nt < 4; ++nt)
#pragma unroll
      for (int hh = 0; hh < 2; ++hh) {
        float2 v2 = make_float2(part[nt][2 * hh], part[nt][2 * hh + 1]);
        *reinterpret_cast<float2*>(&xch[slot * 18 + (nt * 2 + hh) * 2]) = v2;
      }
  }
  __syncthreads();
  if (grp == 0) {
#pragma unroll
    for (int nt = 0; nt < 4; ++nt)
#pragma unroll
      for (int hh = 0; hh < 2; ++hh) {
        float2 v2 = *reinterpret_cast<const float2*>(&xch[slot * 18 + (nt * 2 + hh) * 2]);
        part[nt][2 * hh]     += v2.x;
        part[nt][2 * hh + 1] += v2.y;
      }
#pragma unroll
    for (int r = 0; r < 4; ++r) {
      int qs = g * 64 + wr * 16 + quad * 4 + r;
#pragma unroll
      for (int nt = 0; nt < 4; ++nt)
        o[(size_t)qs * 1024 + qcol + nt * 16 + lr] = f2bf(part[nt][r]);
    }
  }
}

extern "C" void kernel_launch(void* const* d_in, const int* in_sizes, int n_in,
                              void* d_out, int out_size, void* d_ws, size_t ws_size,
                              hipStream_t stream) {
  float* out = (float*)d_out;
  const int nfill = (out_size + 255) / 256;
  if (n_in != 3) { fill_const_kernel<<<nfill, 256, 0, stream>>>(out, out_size, 0.5f); return; }
  int ix = -1, iq = -1, io = -1;
  for (int i = 0; i < 3; ++i) {
    if      (in_sizes[i] == 2097152) ix = i;
    else if (in_sizes[i] == 3145728) iq = i;
    else if (in_sizes[i] == 1048576) io = i;
  }
  if (ix < 0 || iq < 0 || io < 0) { fill_const_kernel<<<nfill, 256, 0, stream>>>(out, out_size, 0.3f); return; }
  const float* x     = (const float*)d_in[ix];
  const float* w_qkv = (const float*)d_in[iq];
  const float* w_out = (const float*)d_in[io];

  char* ws = (char*)d_ws;
  const size_t MB = 1048576;
  const size_t needX = 22 * MB;
  const size_t needY = 20 * MB;

  if (ws_size >= needX) {
    short* qb     = (short*)(ws);
    short* kb     = (short*)(ws + 4 * MB);
    short* vT     = (short*)(ws + 8 * MB);
    short* w_qkvT = (short*)(ws + 12 * MB);
    short* xb     = (short*)(ws + 18 * MB);
    short* o      = (short*)(ws + 12 * MB);   // over dead w_qkvT after g1
    short* w_outT = (short*)(ws + 16 * MB);   // over dead w_qkvT after g1
    cast_f32_bf16<<<2048, 256, 0, stream>>>(x, xb, 2097152);
    transpose_conv<<<dim3(48, 16), 256, 0, stream>>>(w_qkv, w_qkvT, 1024, 3072);
    gemm_tile<0, false, 128><<<dim3(24, 32), 256, 0, stream>>>(xb, w_qkvT, qb, kb, vT, nullptr, 1024, 3072);
    transpose_conv<<<dim3(16, 16), 256, 0, stream>>>(w_out, w_outT, 1024, 1024);
    attn_unified<<<512, 512, 0, stream>>>(qb, kb, vT, o);
    gemm_tile<1, false, 64><<<dim3(16, 32), 256, 0, stream>>>(o, w_outT, nullptr, nullptr, nullptr, out, 1024, 1024);
  } else if (ws_size >= needY) {
    short* w_outT = (short*)(ws);
    short* qb     = (short*)(ws + 2 * MB);
    short* kb     = (short*)(ws + 6 * MB);
    short* vT     = (short*)(ws + 10 * MB);
    short* w_qkvT = (short*)(ws + 14 * MB);
    short* o      = (short*)(ws + 14 * MB);   // over dead w_qkvT after g1
    transpose_conv<<<dim3(48, 16), 256, 0, stream>>>(w_qkv, w_qkvT, 1024, 3072);
    transpose_conv<<<dim3(16, 16), 256, 0, stream>>>(w_out, w_outT, 1024, 1024);
    gemm_tile<0, true, 128><<<dim3(24, 32), 256, 0, stream>>>(x, w_qkvT, qb, kb, vT, nullptr, 1024, 3072);
    attn_unified<<<512, 512, 0, stream>>>(qb, kb, vT, o);
    gemm_tile<1, false, 64><<<dim3(16, 32), 256, 0, stream>>>(o, w_outT, nullptr, nullptr, nullptr, out, 1024, 1024);
  } else {
    fill_const_kernel<<<nfill, 256, 0, stream>>>(out, out_size, 0.2f);
  }
}

// Round 3
// 164.223 us; speedup vs baseline: 1.0480x; 1.0480x over previous
//
#include <hip/hip_runtime.h>
#include <hip/hip_bf16.h>

// MultiScaleAttention: B=1,S=2048,D=1024,H=16,DH=64,WIN=128,DIL=4.
// ESTABLISHED: inputs fp32, output fp32, ws 256 MiB.
// Round-16: fix r15's spill. r15 = 8-wave key-split attn with
// __launch_bounds__(512,4) -> compiler capped VGPR at 64 (empirically the
// 2nd arg acted like CUDA min-BLOCKS: 4 blk x 8 waves = 32 waves/CU -> 64-reg
// cliff) -> ~40 MB scratch traffic (WRITE_SIZE 4KB->28MB), attn 56us.
// Change: __launch_bounds__(512,2) -> VGPR cap 128, demand ~110 fits, target
// 2 blocks/CU = 16 waves/CU spill-free. EVERYTHING else byte-identical to r15.
//  - waves 0-3: keys 0-31 of each tile; waves 4-7: keys 32-63; same q-rows
//  - Q in registers; K/V dbuf LDS shared by both groups; 1 barrier/tile
//  - residue-major tile order; dilated = per-rho slot delta; local = extra
//    mfma(a,b,0) on group wH's half of in-group tile wt2
//  - (o,l) partials pair-combined via LDS at epilogue

typedef __attribute__((ext_vector_type(8))) short s8v;   // 8 bf16
typedef __attribute__((ext_vector_type(4))) float f4v;   // 4 fp32

#define QSCALE 0.18033688011112042f   // 0.125 * log2(e)

__device__ __forceinline__ short f2bf(float f) {
  union { float f; unsigned u; } x; x.f = f;
  unsigned r = (x.u + 0x7FFF + ((x.u >> 16) & 1)) >> 16;   // RNE
  return (short)r;
}
__device__ __forceinline__ f4v mfma16(s8v a, s8v b, f4v c) {
  return __builtin_amdgcn_mfma_f32_16x16x32_bf16(a, b, c, 0, 0, 0);
}
__device__ __forceinline__ void load_lds16(const void* g, void* l) {
  __builtin_amdgcn_global_load_lds(
      (const __attribute__((address_space(1))) unsigned int*)g,
      (__attribute__((address_space(3))) unsigned int*)l, 16, 0, 0);
}
__device__ __forceinline__ float exp2f_fast(float x) {
  return __builtin_amdgcn_exp2f(x);     // v_exp_f32: D = 2^S0
}

__global__ __launch_bounds__(256)
void fill_const_kernel(float* __restrict__ out, int n, float v) {
  int i = blockIdx.x * 256 + threadIdx.x;
  if (i < n) out[i] = v;
}

__global__ __launch_bounds__(256)
void cast_f32_bf16(const float* __restrict__ src, short* __restrict__ dst, int n) {
  int i = (blockIdx.x * 256 + threadIdx.x) * 4;
  if (i < n) {
    float4 v = *reinterpret_cast<const float4*>(&src[i]);
    union { short s[4]; int2 p; } u;
    u.s[0] = f2bf(v.x); u.s[1] = f2bf(v.y); u.s[2] = f2bf(v.z); u.s[3] = f2bf(v.w);
    *reinterpret_cast<int2*>(&dst[i]) = u.p;
  }
}

// ---------- transpose+convert: src fp32 [K][N] -> dst bf16 [N][K] ----------
__global__ __launch_bounds__(256)
void transpose_conv(const float* __restrict__ src, short* __restrict__ dst,
                    int K, int N) {
  __shared__ float T[64][69];
  const int n0 = blockIdx.x * 64, k0 = blockIdx.y * 64;
  const int t = threadIdx.x;
  for (int jb = t; jb < 1024; jb += 256) {
    int r = jb >> 4, c4 = (jb & 15) * 4;
    float4 v = *reinterpret_cast<const float4*>(&src[(size_t)(k0 + r) * N + n0 + c4]);
    T[c4 + 0][r] = v.x; T[c4 + 1][r] = v.y; T[c4 + 2][r] = v.z; T[c4 + 3][r] = v.w;
  }
  __syncthreads();
  for (int jb = t; jb < 512; jb += 256) {
    int n = jb >> 3, k8 = (jb & 7) * 8;
    union { short s[8]; int4 v; } p;
#pragma unroll
    for (int i = 0; i < 8; ++i) p.s[i] = f2bf(T[n][k8 + i]);
    *reinterpret_cast<int4*>(&dst[(size_t)(n0 + n) * K + k0 + k8]) = p.v;
  }
}

// ---------- MFMA GEMM, 64xNT tile, BK=32, C = A * Bt^T ----------
// COUT 0 (g1): C split -> qb (pre-scaled by QSCALE) / kb row-major bf16,
//              V stored to vT in the kappa-permuted layout (see header).
// COUT 1 (g2): C fp32 = acc/3 -> co.
template <int COUT, bool AF32, int NT>
__global__ __launch_bounds__(256)
void gemm_tile(const void* __restrict__ Av, const short* __restrict__ Bt,
               short* __restrict__ qb, short* __restrict__ kb,
               short* __restrict__ vT, float* __restrict__ co,
               int K, int N) {
  __shared__ __align__(16) short As[64 * 32];
  __shared__ __align__(16) short Bs[NT * 32];
  const int tid = threadIdx.x, wave = tid >> 6;
  const int li = tid & 63;
  const int row0 = blockIdx.y * 64, col0 = blockIdx.x * NT;
  const int lr = li & 15, quad = li >> 4, lk = quad * 8;
  constexpr int NTW = NT / 64;          // n-16-tiles per wave (2 or 1)

  f4v acc[4][NTW];
#pragma unroll
  for (int i = 0; i < 4; ++i)
#pragma unroll
    for (int j = 0; j < NTW; ++j) acc[i][j] = (f4v){0.f, 0.f, 0.f, 0.f};

  for (int k0 = 0; k0 < K; k0 += 32) {
    __syncthreads();
#pragma unroll
    for (int u = 0; u < NTW; ++u)
      load_lds16(Bt + (size_t)(col0 + u * 64 + (tid >> 2)) * K + k0 + (tid & 3) * 8,
                 &Bs[u * 2048 + wave * 512]);
    if (AF32) {
      const float* A = (const float*)Av;
#pragma unroll
      for (int c = 0; c < 2; ++c) {
        int j = c * 256 + tid;           // 512 float4 chunks
        int r = j >> 3, c4 = (j & 7) * 4;
        float4 v = *reinterpret_cast<const float4*>(&A[(size_t)(row0 + r) * K + k0 + c4]);
        union { short s[4]; int2 v2; } p;
        p.s[0] = f2bf(v.x); p.s[1] = f2bf(v.y); p.s[2] = f2bf(v.z); p.s[3] = f2bf(v.w);
        *reinterpret_cast<int2*>(&As[r * 32 + c4]) = p.v2;
      }
    } else {
      load_lds16((const short*)Av + (size_t)(row0 + (tid >> 2)) * K + k0 + (tid & 3) * 8,
                 &As[wave * 512]);
    }
    __syncthreads();

    s8v af[4], bfr[NTW];
#pragma unroll
    for (int mt = 0; mt < 4; ++mt)
      af[mt] = *reinterpret_cast<const s8v*>(&As[(mt * 16 + lr) * 32 + lk]);
#pragma unroll
    for (int u = 0; u < NTW; ++u)
      bfr[u] = *reinterpret_cast<const s8v*>(&Bs[(wave * (NT / 4) + u * 16 + lr) * 32 + lk]);
#pragma unroll
    for (int mt = 0; mt < 4; ++mt)
#pragma unroll
      for (int u = 0; u < NTW; ++u)
        acc[mt][u] = mfma16(af[mt], bfr[u], acc[mt][u]);
  }

  // epilogue: C/D layout col=lane&15, row=quad*4+reg
#pragma unroll
  for (int mt = 0; mt < 4; ++mt) {
#pragma unroll
    for (int u = 0; u < NTW; ++u) {
      int gcol = col0 + wave * (NT / 4) + u * 16 + lr;
      int grow0 = row0 + mt * 16 + quad * 4;
      if (COUT == 0) {
        if (gcol >= 2048) {              // vT, kappa-permuted layout
          int d = gcol - 2048;
          int j = grow0 >> 2;            // in-residue position; residue = r
          int gb = ((j >> 6) << 6) + (((j >> 5) & 1) << 5) +
                   ((j & 15) << 1) + ((j >> 4) & 1);
          size_t base = (size_t)d * 2048 + gb;
#pragma unroll
          for (int r = 0; r < 4; ++r)
            vT[base + (r << 9)] = f2bf(acc[mt][u][r]);
        } else {
          short* dst = (gcol < 1024) ? qb : kb;
          float sc = (gcol < 1024) ? QSCALE : 1.0f;
          int c = gcol & 1023;
#pragma unroll
          for (int r = 0; r < 4; ++r)
            dst[(size_t)(grow0 + r) * 1024 + c] = f2bf(acc[mt][u][r] * sc);
        }
      } else {
#pragma unroll
        for (int r = 0; r < 4; ++r)
          co[(size_t)(grow0 + r) * N + gcol] = acc[mt][u][r] * (1.0f / 3.0f);
      }
    }
  }
}

// ---------- unified flash attention, 8-wave key-split -----------------------
// 512 blocks (h=b&15, g=b>>4), 512 threads = 8 waves.
// grp = wave>>2 owns keys [grp*32, +32) of every tile; wr = wave&3 owns
// q-rows g*64 + wr*16 .. +15. 32 key tiles, residue-major (tile t: residue
// rho=t>>3, in-group tile t&7; Ks row n = key n, seq = 4*((t&7)*64+n)+rho).
// Dilated = per-rho accumulator delta on slot r==rho; local = group wH's
// 32 keys of in-group tile wt2=g>>2 (extra mfma(a,b,0) on 4 tiles).
// Partials combined across wave-group pairs via LDS at the end.
__global__ __launch_bounds__(512, 2)
void attn_unified(const short* __restrict__ qb, const short* __restrict__ kb,
                  const short* __restrict__ vT, short* __restrict__ o) {
  __shared__ __align__(16) short Ks[2][64][72];
  __shared__ __align__(16) short Vt[2][64][72];   // [d][kappa]
  __shared__ __align__(16) short Pls[8][16][40];  // per-wave P: 16 rows x 32
  __shared__ float lX[2][4][4][12];               // [grp][wr][quad][l partials]

  const int tid = threadIdx.x;
  const int wave = tid >> 6, li = tid & 63;
  const int grp = wave >> 2, wr = wave & 3;
  const int b = blockIdx.x, h = b & 15, g = b >> 4;
  const int qcol = h * 64;
  const int lr = li & 15, quad = li >> 4, lk = quad * 8;
  const int wt2 = g >> 2;            // in-group tile holding the local window
  const int wH  = (g >> 1) & 1;      // which key-group holds the window
  const bool wgrp = (grp == wH);
  const int sr = tid >> 3, sc8 = (tid & 7) * 8;   // staging row / col

  // Q fragments in registers (qb pre-scaled by QSCALE at g1)
  s8v q0, q1;
  {
    const short* qrow = &qb[(size_t)(g * 64 + wr * 16 + lr) * 1024 + qcol];
    q0 = *reinterpret_cast<const s8v*>(&qrow[lk]);
    q1 = *reinterpret_cast<const s8v*>(&qrow[32 + lk]);
  }

  // stage tile 0 (rho=0, in-group tile 0): one int4 K + one int4 V per thread
  *reinterpret_cast<int4*>(&Ks[0][sr][sc8]) =
      *reinterpret_cast<const int4*>(&kb[(size_t)(sr << 2) * 1024 + qcol + sc8]);
  *reinterpret_cast<int4*>(&Vt[0][sr][sc8]) =
      *reinterpret_cast<const int4*>(&vT[(size_t)(h * 64 + sr) * 2048 + sc8]);
  __syncthreads();

  float l_r[4]   = {0.f, 0.f, 0.f, 0.f};
  float l_loc[4] = {0.f, 0.f, 0.f, 0.f};
  float l_dil[4] = {0.f, 0.f, 0.f, 0.f};
  f4v oacc[4], o_loc[4], o_dil[4];
#pragma unroll
  for (int i = 0; i < 4; ++i) {
    oacc[i]  = (f4v){0.f, 0.f, 0.f, 0.f};
    o_loc[i] = (f4v){0.f, 0.f, 0.f, 0.f};
    o_dil[i] = (f4v){0.f, 0.f, 0.f, 0.f};
  }

  // lane-constant LDS offsets (in shorts)
  const int koffA = ((grp * 2 + 0) * 16 + lr) * 72 + lk;
  const int koffB = ((grp * 2 + 1) * 16 + lr) * 72 + lk;
  const short* KsF = &Ks[0][0][0];
  const short* VtF = &Vt[0][0][0];

#pragma unroll
  for (int rho = 0; rho < 4; ++rho) {
    // snapshot for the dilated delta (slot rho only; static index)
    const float sn0 = oacc[0][rho], sn1 = oacc[1][rho],
                sn2 = oacc[2][rho], sn3 = oacc[3][rho];
    const float lsn = l_r[rho];

#pragma unroll 2
    for (int t8 = 0; t8 < 8; ++t8) {
      const int t = rho * 8 + t8;
      const int cur = t8 & 1, nxt = cur ^ 1;
      const bool pf = (rho < 3) || (t8 < 7);
      const bool wt = wgrp && (t8 == wt2);
      const int cb = cur * 4608;        // 64*72 shorts per buffer

      // prefetch tile t+1 into registers (overlaps compute below)
      int4 kpre, vpre;
      if (pf) {
        const int tn = t + 1;
        const int ksn = ((((tn & 7) << 6) + sr) << 2) + (tn >> 3);
        kpre = *reinterpret_cast<const int4*>(&kb[(size_t)ksn * 1024 + qcol + sc8]);
        vpre = *reinterpret_cast<const int4*>(
            &vT[(size_t)(h * 64 + sr) * 2048 + tn * 64 + sc8]);
      }

      // S = Q K^T for this group's 2 key-16-tiles (contraction over d)
      f4v s4a = (f4v){0.f, 0.f, 0.f, 0.f};
      f4v s4b = (f4v){0.f, 0.f, 0.f, 0.f};
      s4a = mfma16(q0, *reinterpret_cast<const s8v*>(&KsF[cb + koffA]), s4a);
      s4b = mfma16(q0, *reinterpret_cast<const s8v*>(&KsF[cb + koffB]), s4b);
      s4a = mfma16(q1, *reinterpret_cast<const s8v*>(&KsF[cb + koffA + 32]), s4a);
      s4b = mfma16(q1, *reinterpret_cast<const s8v*>(&KsF[cb + koffB + 32]), s4b);

      // static-max softmax: p = exp2(s); pack 2 bf16 per lane-row into Pls
#pragma unroll
      for (int r = 0; r < 4; ++r) {
        float p0 = exp2f_fast(s4a[r]), p1 = exp2f_fast(s4b[r]);
        float ps = p0 + p1;
        l_r[r] += ps;
        if (wt) l_loc[r] += ps;
        union { short s[2]; int v; } pk;
        pk.s[0] = f2bf(p0); pk.s[1] = f2bf(p1);
        *reinterpret_cast<int*>(&Pls[wave][quad * 4 + r][2 * lr]) = pk.v;
      }

      // O += P V over this group's 32 keys (contraction slice grp*32..+31)
      {
        s8v ap = *reinterpret_cast<const s8v*>(&Pls[wave][lr][lk]);
        if (wt) {
#pragma unroll
          for (int nt = 0; nt < 4; ++nt) {
            s8v bv = *reinterpret_cast<const s8v*>(
                &VtF[cb + (nt * 16 + lr) * 72 + grp * 32 + lk]);
            f4v dd = mfma16(ap, bv, (f4v){0.f, 0.f, 0.f, 0.f});
            oacc[nt] += dd;
            o_loc[nt] += dd;
          }
        } else {
#pragma unroll
          for (int nt = 0; nt < 4; ++nt) {
            s8v bv = *reinterpret_cast<const s8v*>(
                &VtF[cb + (nt * 16 + lr) * 72 + grp * 32 + lk]);
            oacc[nt] = mfma16(ap, bv, oacc[nt]);
          }
        }
      }

      // write prefetched tile into the other buffer; single barrier per tile
      if (pf) {
        *reinterpret_cast<int4*>(&Ks[nxt][sr][sc8]) = kpre;
        *reinterpret_cast<int4*>(&Vt[nxt][sr][sc8]) = vpre;
      }
      __syncthreads();
    }

    // dilated delta: q-rows in slot r==rho have residue rho
    l_dil[rho] = l_r[rho] - lsn;
    o_dil[0][rho] = oacc[0][rho] - sn0;
    o_dil[1][rho] = oacc[1][rho] - sn1;
    o_dil[2][rho] = oacc[2][rho] - sn2;
    o_dil[3][rho] = oacc[3][rho] - sn3;
  }

  // ---- epilogue: quad-reduce l's, exchange across wave-group pairs --------
  float lv[12];
#pragma unroll
  for (int r = 0; r < 4; ++r) { lv[r] = l_r[r]; lv[4 + r] = l_loc[r]; lv[8 + r] = l_dil[r]; }
#pragma unroll
  for (int k = 0; k < 12; ++k) {
    lv[k] += __shfl_xor(lv[k], 1, 16);
    lv[k] += __shfl_xor(lv[k], 2, 16);
    lv[k] += __shfl_xor(lv[k], 4, 16);
    lv[k] += __shfl_xor(lv[k], 8, 16);
  }
  if (lr == 0) {
#pragma unroll
    for (int k = 0; k < 12; ++k) lX[grp][wr][quad][k] = lv[k];
  }
  __syncthreads();

  f4v part[4];
#pragma unroll
  for (int r = 0; r < 4; ++r) {
    float lg = lX[0][wr][quad][r]     + lX[1][wr][quad][r];
    float ll = lX[0][wr][quad][4 + r] + lX[1][wr][quad][4 + r];
    float ld = lX[0][wr][quad][8 + r] + lX[1][wr][quad][8 + r];
    float ig = 1.0f / lg, il = 1.0f / ll, id = 1.0f / ld;
#pragma unroll
    for (int nt = 0; nt < 4; ++nt)
      part[nt][r] = oacc[nt][r] * ig + o_loc[nt][r] * il + o_dil[nt][r] * id;
  }

  // pair-combine the blended partials through LDS (reuse Ks region)
  float* xch = reinterpret_cast<float*>(&Ks[0][0][0]);
  const int slot = wr * 64 + li;       // 0..255, stride-18 float rows
  if (grp == 1) {
#pragma unroll
    for (int nt = 0; nt < 4; ++nt)
#pragma unroll
      for (int hh = 0; hh < 2; ++hh) {
        float2 v2 = make_float2(part[nt][2 * hh], part[nt][2 * hh + 1]);
        *reinterpret_cast<float2*>(&xch[slot * 18 + (nt * 2 + hh) * 2]) = v2;
      }
  }
  __syncthreads();
  if (grp == 0) {
#pragma unroll
    for (int nt = 0; nt < 4; ++nt)
#pragma unroll
      for (int hh = 0; hh < 2; ++hh) {
        float2 v2 = *reinterpret_cast<const float2*>(&xch[slot * 18 + (nt * 2 + hh) * 2]);
        part[nt][2 * hh]     += v2.x;
        part[nt][2 * hh + 1] += v2.y;
      }
#pragma unroll
    for (int r = 0; r < 4; ++r) {
      int qs = g * 64 + wr * 16 + quad * 4 + r;
#pragma unroll
      for (int nt = 0; nt < 4; ++nt)
        o[(size_t)qs * 1024 + qcol + nt * 16 + lr] = f2bf(part[nt][r]);
    }
  }
}

extern "C" void kernel_launch(void* const* d_in, const int* in_sizes, int n_in,
                              void* d_out, int out_size, void* d_ws, size_t ws_size,
                              hipStream_t stream) {
  float* out = (float*)d_out;
  const int nfill = (out_size + 255) / 256;
  if (n_in != 3) { fill_const_kernel<<<nfill, 256, 0, stream>>>(out, out_size, 0.5f); return; }
  int ix = -1, iq = -1, io = -1;
  for (int i = 0; i < 3; ++i) {
    if      (in_sizes[i] == 2097152) ix = i;
    else if (in_sizes[i] == 3145728) iq = i;
    else if (in_sizes[i] == 1048576) io = i;
  }
  if (ix < 0 || iq < 0 || io < 0) { fill_const_kernel<<<nfill, 256, 0, stream>>>(out, out_size, 0.3f); return; }
  const float* x     = (const float*)d_in[ix];
  const float* w_qkv = (const float*)d_in[iq];
  const float* w_out = (const float*)d_in[io];

  char* ws = (char*)d_ws;
  const size_t MB = 1048576;
  const size_t needX = 22 * MB;
  const size_t needY = 20 * MB;

  if (ws_size >= needX) {
    short* qb     = (short*)(ws);
    short* kb     = (short*)(ws + 4 * MB);
    short* vT     = (short*)(ws + 8 * MB);
    short* w_qkvT = (short*)(ws + 12 * MB);
    short* xb     = (short*)(ws + 18 * MB);
    short* o      = (short*)(ws + 12 * MB);   // over dead w_qkvT after g1
    short* w_outT = (short*)(ws + 16 * MB);   // over dead w_qkvT after g1
    cast_f32_bf16<<<2048, 256, 0, stream>>>(x, xb, 2097152);
    transpose_conv<<<dim3(48, 16), 256, 0, stream>>>(w_qkv, w_qkvT, 1024, 3072);
    gemm_tile<0, false, 128><<<dim3(24, 32), 256, 0, stream>>>(xb, w_qkvT, qb, kb, vT, nullptr, 1024, 3072);
    transpose_conv<<<dim3(16, 16), 256, 0, stream>>>(w_out, w_outT, 1024, 1024);
    attn_unified<<<512, 512, 0, stream>>>(qb, kb, vT, o);
    gemm_tile<1, false, 64><<<dim3(16, 32), 256, 0, stream>>>(o, w_outT, nullptr, nullptr, nullptr, out, 1024, 1024);
  } else if (ws_size >= needY) {
    short* w_outT = (short*)(ws);
    short* qb     = (short*)(ws + 2 * MB);
    short* kb     = (short*)(ws + 6 * MB);
    short* vT     = (short*)(ws + 10 * MB);
    short* w_qkvT = (short*)(ws + 14 * MB);
    short* o      = (short*)(ws + 14 * MB);   // over dead w_qkvT after g1
    transpose_conv<<<dim3(48, 16), 256, 0, stream>>>(w_qkv, w_qkvT, 1024, 3072);
    transpose_conv<<<dim3(16, 16), 256, 0, stream>>>(w_out, w_outT, 1024, 1024);
    gemm_tile<0, true, 128><<<dim3(24, 32), 256, 0, stream>>>(x, w_qkvT, qb, kb, vT, nullptr, 1024, 3072);
    attn_unified<<<512, 512, 0, stream>>>(qb, kb, vT, o);
    gemm_tile<1, false, 64><<<dim3(16, 32), 256, 0, stream>>>(o, w_outT, nullptr, nullptr, nullptr, out, 1024, 1024);
  } else {
    fill_const_kernel<<<nfill, 256, 0, stream>>>(out, out_size, 0.2f);
  }
}

// Round 4
// 159.341 us; speedup vs baseline: 1.0801x; 1.0306x over previous
//
#include <hip/hip_runtime.h>
#include <hip/hip_bf16.h>

// MultiScaleAttention: B=1,S=2048,D=1024,H=16,DH=64,WIN=128,DIL=4.
// ESTABLISHED: inputs fp32, output fp32, ws 256 MiB.
// Round-17: REGISTER-P attention (swapped QK). r16 showed 8-wave key-split
// at healthy VGPR (80, no spill) is NOT faster than 4-wave r14: the per-tile
// lockstep chain QK->exp2->pack->P.lds_write->wait->P.ds_read->PV->barrier is
// the bottleneck (MfmaUtil 12%, occupancy flat at 18.7% for both).
// Change: compute S^T = mfma(Kfrag, Qfrag) (A/B frag layouts are identical),
// so each lane holds 8 p's of ONE q-row (q=lane&15). With V's kappa layout
// permuted as kappa(m)=8*((m>>2)&3)+4*(m>>4)+(m&3) within each 32-key half
// (baked into gemm vT epilogue; kb staging identity; Vt staging unchanged),
// exp2 results pack DIRECTLY into the PV A-fragment in registers. P never
// touches LDS; Pls deleted; chain shortens by ~200-300 cycles/tile.
//  - local window = physical chunk wH of tile wt2 (perm is half-preserving)
//  - dilated: o-slot r has q-residue r (unchanged); l_dil lane-predicated
//  - l's are per-lane scalars (q=lr); quad shfl-reduce + lX exchange
//  - everything else (gemm/cast/transpose, dbuf, prefetch) as r16

typedef __attribute__((ext_vector_type(8))) short s8v;   // 8 bf16
typedef __attribute__((ext_vector_type(4))) float f4v;   // 4 fp32

#define QSCALE 0.18033688011112042f   // 0.125 * log2(e)

__device__ __forceinline__ short f2bf(float f) {
  union { float f; unsigned u; } x; x.f = f;
  unsigned r = (x.u + 0x7FFF + ((x.u >> 16) & 1)) >> 16;   // RNE
  return (short)r;
}
__device__ __forceinline__ f4v mfma16(s8v a, s8v b, f4v c) {
  return __builtin_amdgcn_mfma_f32_16x16x32_bf16(a, b, c, 0, 0, 0);
}
__device__ __forceinline__ void load_lds16(const void* g, void* l) {
  __builtin_amdgcn_global_load_lds(
      (const __attribute__((address_space(1))) unsigned int*)g,
      (__attribute__((address_space(3))) unsigned int*)l, 16, 0, 0);
}
__device__ __forceinline__ float exp2f_fast(float x) {
  return __builtin_amdgcn_exp2f(x);     // v_exp_f32: D = 2^S0
}

__global__ __launch_bounds__(256)
void fill_const_kernel(float* __restrict__ out, int n, float v) {
  int i = blockIdx.x * 256 + threadIdx.x;
  if (i < n) out[i] = v;
}

__global__ __launch_bounds__(256)
void cast_f32_bf16(const float* __restrict__ src, short* __restrict__ dst, int n) {
  int i = (blockIdx.x * 256 + threadIdx.x) * 4;
  if (i < n) {
    float4 v = *reinterpret_cast<const float4*>(&src[i]);
    union { short s[4]; int2 p; } u;
    u.s[0] = f2bf(v.x); u.s[1] = f2bf(v.y); u.s[2] = f2bf(v.z); u.s[3] = f2bf(v.w);
    *reinterpret_cast<int2*>(&dst[i]) = u.p;
  }
}

// ---------- transpose+convert: src fp32 [K][N] -> dst bf16 [N][K] ----------
__global__ __launch_bounds__(256)
void transpose_conv(const float* __restrict__ src, short* __restrict__ dst,
                    int K, int N) {
  __shared__ float T[64][69];
  const int n0 = blockIdx.x * 64, k0 = blockIdx.y * 64;
  const int t = threadIdx.x;
  for (int jb = t; jb < 1024; jb += 256) {
    int r = jb >> 4, c4 = (jb & 15) * 4;
    float4 v = *reinterpret_cast<const float4*>(&src[(size_t)(k0 + r) * N + n0 + c4]);
    T[c4 + 0][r] = v.x; T[c4 + 1][r] = v.y; T[c4 + 2][r] = v.z; T[c4 + 3][r] = v.w;
  }
  __syncthreads();
  for (int jb = t; jb < 512; jb += 256) {
    int n = jb >> 3, k8 = (jb & 7) * 8;
    union { short s[8]; int4 v; } p;
#pragma unroll
    for (int i = 0; i < 8; ++i) p.s[i] = f2bf(T[n][k8 + i]);
    *reinterpret_cast<int4*>(&dst[(size_t)(n0 + n) * K + k0 + k8]) = p.v;
  }
}

// ---------- MFMA GEMM, 64xNT tile, BK=32, C = A * Bt^T ----------
// COUT 0 (g1): C split -> qb (pre-scaled by QSCALE) / kb row-major bf16,
//              V stored to vT in the kappa-permuted layout (see header).
// COUT 1 (g2): C fp32 = acc/3 -> co.
template <int COUT, bool AF32, int NT>
__global__ __launch_bounds__(256)
void gemm_tile(const void* __restrict__ Av, const short* __restrict__ Bt,
               short* __restrict__ qb, short* __restrict__ kb,
               short* __restrict__ vT, float* __restrict__ co,
               int K, int N) {
  __shared__ __align__(16) short As[64 * 32];
  __shared__ __align__(16) short Bs[NT * 32];
  const int tid = threadIdx.x, wave = tid >> 6;
  const int li = tid & 63;
  const int row0 = blockIdx.y * 64, col0 = blockIdx.x * NT;
  const int lr = li & 15, quad = li >> 4, lk = quad * 8;
  constexpr int NTW = NT / 64;          // n-16-tiles per wave (2 or 1)

  f4v acc[4][NTW];
#pragma unroll
  for (int i = 0; i < 4; ++i)
#pragma unroll
    for (int j = 0; j < NTW; ++j) acc[i][j] = (f4v){0.f, 0.f, 0.f, 0.f};

  for (int k0 = 0; k0 < K; k0 += 32) {
    __syncthreads();
#pragma unroll
    for (int u = 0; u < NTW; ++u)
      load_lds16(Bt + (size_t)(col0 + u * 64 + (tid >> 2)) * K + k0 + (tid & 3) * 8,
                 &Bs[u * 2048 + wave * 512]);
    if (AF32) {
      const float* A = (const float*)Av;
#pragma unroll
      for (int c = 0; c < 2; ++c) {
        int j = c * 256 + tid;           // 512 float4 chunks
        int r = j >> 3, c4 = (j & 7) * 4;
        float4 v = *reinterpret_cast<const float4*>(&A[(size_t)(row0 + r) * K + k0 + c4]);
        union { short s[4]; int2 v2; } p;
        p.s[0] = f2bf(v.x); p.s[1] = f2bf(v.y); p.s[2] = f2bf(v.z); p.s[3] = f2bf(v.w);
        *reinterpret_cast<int2*>(&As[r * 32 + c4]) = p.v2;
      }
    } else {
      load_lds16((const short*)Av + (size_t)(row0 + (tid >> 2)) * K + k0 + (tid & 3) * 8,
                 &As[wave * 512]);
    }
    __syncthreads();

    s8v af[4], bfr[NTW];
#pragma unroll
    for (int mt = 0; mt < 4; ++mt)
      af[mt] = *reinterpret_cast<const s8v*>(&As[(mt * 16 + lr) * 32 + lk]);
#pragma unroll
    for (int u = 0; u < NTW; ++u)
      bfr[u] = *reinterpret_cast<const s8v*>(&Bs[(wave * (NT / 4) + u * 16 + lr) * 32 + lk]);
#pragma unroll
    for (int mt = 0; mt < 4; ++mt)
#pragma unroll
      for (int u = 0; u < NTW; ++u)
        acc[mt][u] = mfma16(af[mt], bfr[u], acc[mt][u]);
  }

  // epilogue: C/D layout col=lane&15, row=quad*4+reg
#pragma unroll
  for (int mt = 0; mt < 4; ++mt) {
#pragma unroll
    for (int u = 0; u < NTW; ++u) {
      int gcol = col0 + wave * (NT / 4) + u * 16 + lr;
      int grow0 = row0 + mt * 16 + quad * 4;
      if (COUT == 0) {
        if (gcol >= 2048) {              // vT, kappa-permuted layout
          int d = gcol - 2048;
          int j = grow0 >> 2;            // in-residue position; residue = r
          int gb = ((j >> 6) << 6) + (((j >> 5) & 1) << 5) +
                   (((j >> 2) & 3) << 3) + (((j >> 4) & 1) << 2) + (j & 3);
          size_t base = (size_t)d * 2048 + gb;
#pragma unroll
          for (int r = 0; r < 4; ++r)
            vT[base + (r << 9)] = f2bf(acc[mt][u][r]);
        } else {
          short* dst = (gcol < 1024) ? qb : kb;
          float sc = (gcol < 1024) ? QSCALE : 1.0f;
          int c = gcol & 1023;
#pragma unroll
          for (int r = 0; r < 4; ++r)
            dst[(size_t)(grow0 + r) * 1024 + c] = f2bf(acc[mt][u][r] * sc);
        }
      } else {
#pragma unroll
        for (int r = 0; r < 4; ++r)
          co[(size_t)(grow0 + r) * N + gcol] = acc[mt][u][r] * (1.0f / 3.0f);
      }
    }
  }
}

// ---------- unified flash attention, 8-wave key-split, register-P -----------
// 512 blocks (h=b&15, g=b>>4), 512 threads = 8 waves.
// grp = wave>>2 owns keys [grp*32,+32) of every tile (physical chunk = grp,
// identity staging: Ks row n = logical key offset n); wr = wave&3 owns q-rows
// g*64 + wr*16 .. +15. 32 key tiles, residue-major (tile t: rho=t>>3,
// in-group tile t8=t&7; Ks row n -> seq = 4*(t8*64+n)+rho).
// QK swapped: s4x = mfma(Kfrag, Qfrag) -> lane holds p's for q=lr, keys at
// Ks-pos grp*32 + {b*16 + quad*4 + r}. Vt kappa = 8*((m>>2)&3)+4*(m>>4)+(m&3)
// within each half => exp2'd p's pack directly as PV A-frag (no LDS for P).
// Dilated = per-rho slot delta (o) / lane-predicated delta (l); local = extra
// zero-C PV mfma on grp wH's chunk of tile wt2=g>>2.
__global__ __launch_bounds__(512, 2)
void attn_unified(const short* __restrict__ qb, const short* __restrict__ kb,
                  const short* __restrict__ vT, short* __restrict__ o) {
  __shared__ __align__(16) short Ks[2][64][72];
  __shared__ __align__(16) short Vt[2][64][72];   // [d][kappa]
  __shared__ float lX[2][4][16][4];               // [grp][wr][q][{lg,ll,ld}]

  const int tid = threadIdx.x;
  const int wave = tid >> 6, li = tid & 63;
  const int grp = wave >> 2, wr = wave & 3;
  const int b = blockIdx.x, h = b & 15, g = b >> 4;
  const int qcol = h * 64;
  const int lr = li & 15, quad = li >> 4, lk = quad * 8;
  const int wt2 = g >> 2;            // in-group tile holding the local window
  const int wH  = (g >> 1) & 1;      // which key-group holds the window
  const bool wgrp = (grp == wH);
  const int sr = tid >> 3, sc8 = (tid & 7) * 8;   // staging row / col

  // Q fragments in registers (qb pre-scaled by QSCALE at g1); B-operand:
  // lane holds Q[q=lr][d = quad*8 .. +8] (+32 for chunk 1)
  s8v q0, q1;
  {
    const short* qrow = &qb[(size_t)(g * 64 + wr * 16 + lr) * 1024 + qcol];
    q0 = *reinterpret_cast<const s8v*>(&qrow[lk]);
    q1 = *reinterpret_cast<const s8v*>(&qrow[32 + lk]);
  }

  // stage tile 0 (rho=0, t8=0): one int4 K + one int4 V per thread
  *reinterpret_cast<int4*>(&Ks[0][sr][sc8]) =
      *reinterpret_cast<const int4*>(&kb[(size_t)(sr << 2) * 1024 + qcol + sc8]);
  *reinterpret_cast<int4*>(&Vt[0][sr][sc8]) =
      *reinterpret_cast<const int4*>(&vT[(size_t)(h * 64 + sr) * 2048 + sc8]);
  __syncthreads();

  float l_r = 0.f, l_loc = 0.f, l_dil = 0.f;
  f4v oacc[4], o_loc[4], o_dil[4];
#pragma unroll
  for (int i = 0; i < 4; ++i) {
    oacc[i]  = (f4v){0.f, 0.f, 0.f, 0.f};
    o_loc[i] = (f4v){0.f, 0.f, 0.f, 0.f};
    o_dil[i] = (f4v){0.f, 0.f, 0.f, 0.f};
  }

  // lane-constant LDS offsets (shorts); K used as MFMA *A* operand now
  const int koffA = ((grp * 2 + 0) * 16 + lr) * 72 + lk;
  const int koffB = ((grp * 2 + 1) * 16 + lr) * 72 + lk;
  const short* KsF = &Ks[0][0][0];
  const short* VtF = &Vt[0][0][0];

#pragma unroll
  for (int rho = 0; rho < 4; ++rho) {
    // snapshot for the dilated delta (slot rho only; static index)
    const float sn0 = oacc[0][rho], sn1 = oacc[1][rho],
                sn2 = oacc[2][rho], sn3 = oacc[3][rho];
    const float lsn = l_r;

#pragma unroll 2
    for (int t8 = 0; t8 < 8; ++t8) {
      const int t = rho * 8 + t8;
      const int cur = t8 & 1, nxt = cur ^ 1;
      const bool pf = (rho < 3) || (t8 < 7);
      const bool wt = wgrp && (t8 == wt2);
      const int cb = cur * 4608;        // 64*72 shorts per buffer

      // prefetch tile t+1 into registers (overlaps compute below)
      int4 kpre, vpre;
      if (pf) {
        const int tn = t + 1;
        const int ksn = ((((tn & 7) << 6) + sr) << 2) + (tn >> 3);
        kpre = *reinterpret_cast<const int4*>(&kb[(size_t)ksn * 1024 + qcol + sc8]);
        vpre = *reinterpret_cast<const int4*>(
            &vT[(size_t)(h * 64 + sr) * 2048 + tn * 64 + sc8]);
      }

      // S^T = K Q^T for this group's 2 key-16-tiles (swapped operands):
      // lane: q = lr, keys = Ks-pos grp*32 + {quad*4+r} (a) / {16+quad*4+r} (b)
      f4v s4a = (f4v){0.f, 0.f, 0.f, 0.f};
      f4v s4b = (f4v){0.f, 0.f, 0.f, 0.f};
      s4a = mfma16(*reinterpret_cast<const s8v*>(&KsF[cb + koffA]), q0, s4a);
      s4b = mfma16(*reinterpret_cast<const s8v*>(&KsF[cb + koffB]), q0, s4b);
      s4a = mfma16(*reinterpret_cast<const s8v*>(&KsF[cb + koffA + 32]), q1, s4a);
      s4b = mfma16(*reinterpret_cast<const s8v*>(&KsF[cb + koffB + 32]), q1, s4b);

      // static-max softmax: p = exp2(s); pack PV A-frag IN REGISTERS.
      // A-frag k-slot j: j=r <- tile a, j=4+r <- tile b (matches Vt kappa).
      union { short s[8]; s8v v; } pk;
      float ps = 0.f;
#pragma unroll
      for (int r = 0; r < 4; ++r) {
        float p0 = exp2f_fast(s4a[r]), p1 = exp2f_fast(s4b[r]);
        ps += p0 + p1;
        pk.s[r] = f2bf(p0); pk.s[4 + r] = f2bf(p1);
      }
      l_r += ps;
      if (wt) l_loc += ps;

      // O += P V over this group's 32 keys (kappa chunk grp)
      if (wt) {
#pragma unroll
        for (int nt = 0; nt < 4; ++nt) {
          s8v bv = *reinterpret_cast<const s8v*>(
              &VtF[cb + (nt * 16 + lr) * 72 + grp * 32 + lk]);
          f4v dd = mfma16(pk.v, bv, (f4v){0.f, 0.f, 0.f, 0.f});
          oacc[nt] += dd;
          o_loc[nt] += dd;
        }
      } else {
#pragma unroll
        for (int nt = 0; nt < 4; ++nt) {
          s8v bv = *reinterpret_cast<const s8v*>(
              &VtF[cb + (nt * 16 + lr) * 72 + grp * 32 + lk]);
          oacc[nt] = mfma16(pk.v, bv, oacc[nt]);
        }
      }

      // write prefetched tile into the other buffer; single barrier per tile
      if (pf) {
        *reinterpret_cast<int4*>(&Ks[nxt][sr][sc8]) = kpre;
        *reinterpret_cast<int4*>(&Vt[nxt][sr][sc8]) = vpre;
      }
      __syncthreads();
    }

    // dilated delta: o-slot r==rho has q-residue rho; l lane-predicated
    if (((lr ^ rho) & 3) == 0) l_dil = l_r - lsn;
    o_dil[0][rho] = oacc[0][rho] - sn0;
    o_dil[1][rho] = oacc[1][rho] - sn1;
    o_dil[2][rho] = oacc[2][rho] - sn2;
    o_dil[3][rho] = oacc[3][rho] - sn3;
  }

  // ---- epilogue: reduce l over quads (keys), exchange across grp pair -----
  l_r   += __shfl_xor(l_r, 16);   l_r   += __shfl_xor(l_r, 32);
  l_loc += __shfl_xor(l_loc, 16); l_loc += __shfl_xor(l_loc, 32);
  l_dil += __shfl_xor(l_dil, 16); l_dil += __shfl_xor(l_dil, 32);
  if (li < 16) {
    lX[grp][wr][li][0] = l_r;
    lX[grp][wr][li][1] = l_loc;
    lX[grp][wr][li][2] = l_dil;
  }
  __syncthreads();

  f4v part[4];
#pragma unroll
  for (int r = 0; r < 4; ++r) {
    int q4 = quad * 4 + r;
    float lg = lX[0][wr][q4][0] + lX[1][wr][q4][0];
    float ll = lX[0][wr][q4][1] + lX[1][wr][q4][1];
    float ld = lX[0][wr][q4][2] + lX[1][wr][q4][2];
    float ig = 1.0f / lg, il = 1.0f / ll, id = 1.0f / ld;
#pragma unroll
    for (int nt = 0; nt < 4; ++nt)
      part[nt][r] = oacc[nt][r] * ig + o_loc[nt][r] * il + o_dil[nt][r] * id;
  }

  // pair-combine the blended partials through LDS (reuse Ks region)
  float* xch = reinterpret_cast<float*>(&Ks[0][0][0]);
  const int slot = wr * 64 + li;       // 0..255, stride-18 float rows
  if (grp == 1) {
#pragma unroll
    for (int nt = 0; nt < 4; ++nt)
#pragma unroll
      for (int hh = 0; hh < 2; ++hh) {
        float2 v2 = make_float2(part[nt][2 * hh], part[nt][2 * hh + 1]);
        *reinterpret_cast<float2*>(&xch[slot * 18 + (nt * 2 + hh) * 2]) = v2;
      }
  }
  __syncthreads();
  if (grp == 0) {
#pragma unroll
    for (int nt = 0; nt < 4; ++nt)
#pragma unroll
      for (int hh = 0; hh < 2; ++hh) {
        float2 v2 = *reinterpret_cast<const float2*>(&xch[slot * 18 + (nt * 2 + hh) * 2]);
        part[nt][2 * hh]     += v2.x;
        part[nt][2 * hh + 1] += v2.y;
      }
#pragma unroll
    for (int r = 0; r < 4; ++r) {
      int qs = g * 64 + wr * 16 + quad * 4 + r;
#pragma unroll
      for (int nt = 0; nt < 4; ++nt)
        o[(size_t)qs * 1024 + qcol + nt * 16 + lr] = f2bf(part[nt][r]);
    }
  }
}

extern "C" void kernel_launch(void* const* d_in, const int* in_sizes, int n_in,
                              void* d_out, int out_size, void* d_ws, size_t ws_size,
                              hipStream_t stream) {
  float* out = (float*)d_out;
  const int nfill = (out_size + 255) / 256;
  if (n_in != 3) { fill_const_kernel<<<nfill, 256, 0, stream>>>(out, out_size, 0.5f); return; }
  int ix = -1, iq = -1, io = -1;
  for (int i = 0; i < 3; ++i) {
    if      (in_sizes[i] == 2097152) ix = i;
    else if (in_sizes[i] == 3145728) iq = i;
    else if (in_sizes[i] == 1048576) io = i;
  }
  if (ix < 0 || iq < 0 || io < 0) { fill_const_kernel<<<nfill, 256, 0, stream>>>(out, out_size, 0.3f); return; }
  const float* x     = (const float*)d_in[ix];
  const float* w_qkv = (const float*)d_in[iq];
  const float* w_out = (const float*)d_in[io];

  char* ws = (char*)d_ws;
  const size_t MB = 1048576;
  const size_t needX = 22 * MB;
  const size_t needY = 20 * MB;

  if (ws_size >= needX) {
    short* qb     = (short*)(ws);
    short* kb     = (short*)(ws + 4 * MB);
    short* vT     = (short*)(ws + 8 * MB);
    short* w_qkvT = (short*)(ws + 12 * MB);
    short* xb     = (short*)(ws + 18 * MB);
    short* o      = (short*)(ws + 12 * MB);   // over dead w_qkvT after g1
    short* w_outT = (short*)(ws + 16 * MB);   // over dead w_qkvT after g1
    cast_f32_bf16<<<2048, 256, 0, stream>>>(x, xb, 2097152);
    transpose_conv<<<dim3(48, 16), 256, 0, stream>>>(w_qkv, w_qkvT, 1024, 3072);
    gemm_tile<0, false, 128><<<dim3(24, 32), 256, 0, stream>>>(xb, w_qkvT, qb, kb, vT, nullptr, 1024, 3072);
    transpose_conv<<<dim3(16, 16), 256, 0, stream>>>(w_out, w_outT, 1024, 1024);
    attn_unified<<<512, 512, 0, stream>>>(qb, kb, vT, o);
    gemm_tile<1, false, 64><<<dim3(16, 32), 256, 0, stream>>>(o, w_outT, nullptr, nullptr, nullptr, out, 1024, 1024);
  } else if (ws_size >= needY) {
    short* w_outT = (short*)(ws);
    short* qb     = (short*)(ws + 2 * MB);
    short* kb     = (short*)(ws + 6 * MB);
    short* vT     = (short*)(ws + 10 * MB);
    short* w_qkvT = (short*)(ws + 14 * MB);
    short* o      = (short*)(ws + 14 * MB);   // over dead w_qkvT after g1
    transpose_conv<<<dim3(48, 16), 256, 0, stream>>>(w_qkv, w_qkvT, 1024, 3072);
    transpose_conv<<<dim3(16, 16), 256, 0, stream>>>(w_out, w_outT, 1024, 1024);
    gemm_tile<0, true, 128><<<dim3(24, 32), 256, 0, stream>>>(x, w_qkvT, qb, kb, vT, nullptr, 1024, 3072);
    attn_unified<<<512, 512, 0, stream>>>(qb, kb, vT, o);
    gemm_tile<1, false, 64><<<dim3(16, 32), 256, 0, stream>>>(o, w_outT, nullptr, nullptr, nullptr, out, 1024, 1024);
  } else {
    fill_const_kernel<<<nfill, 256, 0, stream>>>(out, out_size, 0.2f);
  }
}